// Round 15
// baseline (492.710 us; speedup 1.0000x reference)
//
#include <hip/hip_runtime.h>
#include <hip/hip_bf16.h>

#define NN 30000
#define NE 480000
#define NROWT 1875   // NN/16

typedef __attribute__((ext_vector_type(8))) short short8;
typedef __attribute__((ext_vector_type(4))) float floatx4;

__device__ __forceinline__ short f2bs(float f) {
    __hip_bfloat16 h = __float2bfloat16(f);
    return *reinterpret_cast<short*>(&h);
}

__device__ __forceinline__ short2 split_bf16(float f) {
    __hip_bfloat16 h = __float2bfloat16(f);          // RTNE high part
    float r = f - __bfloat162float(h);               // residual, |r| <= 2^-9 |f|
    __hip_bfloat16 l = __float2bfloat16(r);
    short2 out;
    out.x = *reinterpret_cast<short*>(&h);
    out.y = *reinterpret_cast<short*>(&l);
    return out;
}

// ---- one fused presplit of ALL weights: fp32 W[K][N] -> transposed bf16 hi/lo [Npad][K] ----
__global__ void presplit_all(const float* __restrict__ ew, const float* __restrict__ nw,
                             const float* __restrict__ m1w, const float* __restrict__ m2w,
                             const float* __restrict__ lw,
                             short* __restrict__ ew_h, short* __restrict__ ew_l,
                             short* __restrict__ nw_h, short* __restrict__ nw_l,
                             short* __restrict__ m1_h, short* __restrict__ m1_l,
                             short* __restrict__ m2_h, short* __restrict__ m2_l,
                             short* __restrict__ lw_h, short* __restrict__ lw_l)
{
    int i = blockIdx.x * 256 + threadIdx.x;
    if (i < 2048) {                       // ew [16][128] -> [128][16]
        int k = i >> 7, n = i & 127;
        short2 s = split_bf16(ew[i]);
        ew_h[n * 16 + k] = s.x; ew_l[n * 16 + k] = s.y;
    } else if (i < 10240) {               // nw [64][128] -> [128][64]
        int j = i - 2048;
        int k = j >> 7, n = j & 127;
        short2 s = split_bf16(nw[j]);
        nw_h[n * 64 + k] = s.x; nw_l[n * 64 + k] = s.y;
    } else if (i < 108544) {              // m1 3x[128][256] -> 3x[256][128]
        int j = i - 10240;
        int l = j >> 15, jj = j & 32767;
        int k = jj >> 8, n = jj & 255;
        short2 s = split_bf16(m1w[j]);
        m1_h[(size_t)l * 32768 + n * 128 + k] = s.x;
        m1_l[(size_t)l * 32768 + n * 128 + k] = s.y;
    } else if (i < 206848) {              // m2 3x[256][128] -> 3x[128][256]
        int j = i - 108544;
        int l = j >> 15, jj = j & 32767;
        int k = jj >> 7, n = jj & 127;
        short2 s = split_bf16(m2w[j]);
        m2_h[(size_t)l * 32768 + n * 256 + k] = s.x;
        m2_l[(size_t)l * 32768 + n * 256 + k] = s.y;
    } else if (i < 208896) {              // lw [128][10] -> [16][128] (rows>=10 zero)
        int j = i - 206848;
        int k = j >> 4, n = j & 15;
        short2 s = (n < 10) ? split_bf16(lw[k * 10 + n]) : short2{0, 0};
        lw_h[n * 128 + k] = s.x; lw_l[n * 128 + k] = s.y;
    }
}

// ---- node encoder GEMM (A fp32, split in-kernel). One 16x16 tile/wave.
// Also emits packed bf16 pair view hp[node][64] u32 for agg gathers.
template<int K, int N>
__launch_bounds__(256)
__global__ void gemm_a32(const float* __restrict__ A, const short* __restrict__ Bh,
                         const short* __restrict__ Bl, const float* __restrict__ bias,
                         float* __restrict__ C, unsigned* __restrict__ hp, int total_waves)
{
    int wave = ((blockIdx.x * 256) + threadIdx.x) >> 6;
    if (wave >= total_waves) return;
    constexpr int NT = N / 16;
    const int mt = wave / NT, nt = wave % NT;
    const int lane = threadIdx.x & 63;
    const int l15 = lane & 15, quad = lane >> 4;
    const int row = mt * 16 + l15;
    const int col = nt * 16 + l15;
    floatx4 acc = {0.f, 0.f, 0.f, 0.f};
#pragma unroll
    for (int k0 = 0; k0 < K; k0 += 32) {
        const int kb = k0 + quad * 8;
        short8 ah, al;
        const float* ap = A + (size_t)row * K + kb;
        floatx4 a0 = *(const floatx4*)ap;
        floatx4 a1 = *(const floatx4*)(ap + 4);
#pragma unroll
        for (int j = 0; j < 4; j++) {
            short2 s0 = split_bf16(a0[j]); ah[j] = s0.x; al[j] = s0.y;
            short2 s1 = split_bf16(a1[j]); ah[j + 4] = s1.x; al[j + 4] = s1.y;
        }
        short8 bh = *(const short8*)(Bh + (size_t)col * K + kb);
        short8 bl = *(const short8*)(Bl + (size_t)col * K + kb);
        acc = __builtin_amdgcn_mfma_f32_16x16x32_bf16(ah, bh, acc, 0, 0, 0);
        acc = __builtin_amdgcn_mfma_f32_16x16x32_bf16(al, bh, acc, 0, 0, 0);
        acc = __builtin_amdgcn_mfma_f32_16x16x32_bf16(ah, bl, acc, 0, 0, 0);
    }
    float bv = bias[col];
#pragma unroll
    for (int r = 0; r < 4; r++) {
        int ro = mt * 16 + quad * 4 + r;   // C/D: col=lane&15, row=quad*4+reg
        float v = acc[r] + bv;
        C[(size_t)ro * N + col] = v;
        int mb = (int)(unsigned short)f2bs(v);
        int ob = __shfl_xor(mb, 1, 64);
        if ((l15 & 1) == 0)
            hp[(size_t)ro * 64 + nt * 8 + (l15 >> 1)] = (unsigned)mb | ((unsigned)ob << 16);
    }
}

// ---- generic pre-split GEMM (classifier): 16 x (16*NTW) tile per wave ----
template<int K, int NTOT, int NTW, int NREAL>
__launch_bounds__(256)
__global__ void gemm_s(const short* __restrict__ Ah, const short* __restrict__ Al,
                       const short* __restrict__ Bh, const short* __restrict__ Bl,
                       const float* __restrict__ bias, float* __restrict__ C, int total_waves)
{
    int wave = ((blockIdx.x * 256) + threadIdx.x) >> 6;
    if (wave >= total_waves) return;
    constexpr int NG = NTOT / (16 * NTW);
    const int mt = wave / NG, g = wave % NG;
    const int lane = threadIdx.x & 63;
    const int l15 = lane & 15, quad = lane >> 4;
    const int row = mt * 16 + l15;
    floatx4 acc[NTW];
#pragma unroll
    for (int t = 0; t < NTW; t++) acc[t] = {0.f, 0.f, 0.f, 0.f};
#pragma unroll
    for (int k0 = 0; k0 < K; k0 += 32) {
        const int kb = k0 + quad * 8;
        short8 ah = *(const short8*)(Ah + (size_t)row * K + kb);
        short8 al = *(const short8*)(Al + (size_t)row * K + kb);
#pragma unroll
        for (int t = 0; t < NTW; t++) {
            int col = g * NTW * 16 + t * 16 + l15;
            short8 bh = *(const short8*)(Bh + (size_t)col * K + kb);
            short8 bl = *(const short8*)(Bl + (size_t)col * K + kb);
            acc[t] = __builtin_amdgcn_mfma_f32_16x16x32_bf16(ah, bh, acc[t], 0, 0, 0);
            acc[t] = __builtin_amdgcn_mfma_f32_16x16x32_bf16(al, bh, acc[t], 0, 0, 0);
            acc[t] = __builtin_amdgcn_mfma_f32_16x16x32_bf16(ah, bl, acc[t], 0, 0, 0);
        }
    }
#pragma unroll
    for (int t = 0; t < NTW; t++) {
        int col = g * NTW * 16 + t * 16 + l15;
        if (col < NREAL) {
            float bv = bias[col];
#pragma unroll
            for (int r = 0; r < 4; r++) {
                int ro = mt * 16 + quad * 4 + r;
                C[(size_t)ro * NREAL + col] = acc[t][r] + bv;
            }
        }
    }
}

// ---- edge-encoder GEMM: gathers attr via eidx, writes 4-edge-interleaved ea4 layout ----
__launch_bounds__(256)
__global__ void gemm_ea(const float* __restrict__ edge_attr, const int* __restrict__ eidx_csr,
                        const short* __restrict__ Bh, const short* __restrict__ Bl,
                        const float* __restrict__ bias, unsigned* __restrict__ ea4)
{
    __shared__ short tile[2][16][132];
    const int wv = threadIdx.x >> 6;
    const int sub = wv >> 1, g = wv & 1;
    const int lane = threadIdx.x & 63;
    const int l15 = lane & 15, quad = lane >> 4;
    const int p = blockIdx.x * 32 + sub * 16 + l15;
    short8 a;
    if (quad < 2) {
        int e = eidx_csr[p];
        const float* ap = edge_attr + (size_t)e * 16 + quad * 8;
        floatx4 a0 = *(const floatx4*)ap;
        floatx4 a1 = *(const floatx4*)(ap + 4);
#pragma unroll
        for (int j = 0; j < 4; j++) { a[j] = f2bs(a0[j]); a[j + 4] = f2bs(a1[j]); }
    } else {
#pragma unroll
        for (int j = 0; j < 8; j++) a[j] = 0;
    }
    floatx4 acc[4];
#pragma unroll
    for (int t = 0; t < 4; t++) acc[t] = {0.f, 0.f, 0.f, 0.f};
#pragma unroll
    for (int t = 0; t < 4; t++) {
        int col = g * 64 + t * 16 + l15;
        short8 bh, bl;
        if (quad < 2) {
            bh = *(const short8*)(Bh + (size_t)col * 16 + quad * 8);
            bl = *(const short8*)(Bl + (size_t)col * 16 + quad * 8);
        } else {
#pragma unroll
            for (int j = 0; j < 8; j++) { bh[j] = 0; bl[j] = 0; }
        }
        acc[t] = __builtin_amdgcn_mfma_f32_16x16x32_bf16(a, bh, acc[t], 0, 0, 0);
        acc[t] = __builtin_amdgcn_mfma_f32_16x16x32_bf16(a, bl, acc[t], 0, 0, 0);
    }
#pragma unroll
    for (int t = 0; t < 4; t++) {
        int col = g * 64 + t * 16 + l15;
        float bv = bias[col];
#pragma unroll
        for (int r = 0; r < 4; r++)
            tile[sub][quad * 4 + r][col] = f2bs(acc[t][r] + bv);
    }
    __syncthreads();
#pragma unroll
    for (int c = 0; c < 2; c++) {
        int idx = threadIdx.x + 256 * c;          // 0..511
        int o = idx * 16;
        int g4l = o >> 10;
        int lp = (o & 1023) >> 4;
        unsigned u[4];
#pragma unroll
        for (int e = 0; e < 4; e++) {
            int rl = g4l * 4 + e;
            u[e] = *(const unsigned*)&tile[rl >> 4][rl & 15][2 * lp];
        }
        uint4 val = make_uint4(u[0], u[1], u[2], u[3]);
        *(uint4*)((char*)ea4 + (size_t)blockIdx.x * 8192 + o) = val;
    }
}

// ---- zero fill ----
__global__ void zero_kernel(int* __restrict__ p, int n)
{
    int i = blockIdx.x * 256 + threadIdx.x;
    if (i < n) p[i] = 0;
}

// ---- CSR build ----
__global__ void hist_kernel(const int* __restrict__ dst, int* __restrict__ count)
{
    int e = blockIdx.x * 256 + threadIdx.x;
    if (e < NE) atomicAdd(count + dst[e], 1);
}

__launch_bounds__(1024)
__global__ void scan_kernel(const int* __restrict__ count, int* __restrict__ rowptr)
{
    __shared__ int part[1024];
    const int t = threadIdx.x;
    const int CH = (NN + 1023) / 1024;          // 30
    const int base = t * CH;
    int sum = 0;
    for (int j = 0; j < CH; j++) {
        int idx = base + j;
        if (idx < NN) sum += count[idx];
    }
    part[t] = sum;
    __syncthreads();
    for (int d = 1; d < 1024; d <<= 1) {
        int v = (t >= d) ? part[t - d] : 0;
        __syncthreads();
        part[t] += v;
        __syncthreads();
    }
    int off = (t == 0) ? 0 : part[t - 1];
    for (int j = 0; j < CH; j++) {
        int idx = base + j;
        if (idx < NN) { rowptr[idx] = off; off += count[idx]; }
    }
    if (t == 1023) rowptr[NN] = part[1023];
}

__global__ void scatter_kernel(const int* __restrict__ src, const int* __restrict__ dst,
                               const int* __restrict__ rowptr, int* __restrict__ cursor,
                               int* __restrict__ src_csr, int* __restrict__ eidx_csr)
{
    int e = blockIdx.x * 256 + threadIdx.x;
    if (e >= NE) return;
    int d = dst[e];
    int pos = rowptr[d] + atomicAdd(cursor + d, 1);
    src_csr[pos] = src[e];
    eidx_csr[pos] = e;
}

// ---- fused aggregation v4: bf16 hp gather, masked 4-edge groups, 2 waves per node ----
// Waves (even,odd) of a pair split the node's groups by parity; combine via LDS.
__device__ __forceinline__ void updm(float hv, float av, float tt, float m,
                                     float& s, float& n)
{
    float g = fmaxf(hv + av, 0.f) + 1e-7f;   // msg
    float e = __expf(g * tt) * m;             // exp(logit), masked
    s += e;
    n = fmaf(g, e, n);
}

__launch_bounds__(256)
__global__ void agg_kernel(const unsigned* __restrict__ hp, const float* __restrict__ hres,
                           const uint4* __restrict__ ea4q, const int* __restrict__ src_csr,
                           const int* __restrict__ rowptr, const float* __restrict__ tptr,
                           int layer, unsigned* __restrict__ Zp)
{
    __shared__ float4 part[4][64];
    const int wv = threadIdx.x >> 6;
    const int node = blockIdx.x * 2 + (wv >> 1);   // grid = NN/2 exact
    const int par = wv & 1;
    const int lane = threadIdx.x & 63;
    const float tt = tptr[layer];
    const int start = rowptr[node];
    const int end = rowptr[node + 1];
    const int g0 = start >> 2, g1 = (end + 3) >> 2;
    float s0a = 0.f, s1a = 0.f, n0a = 0.f, n1a = 0.f;
    float s0b = 0.f, s1b = 0.f, n0b = 0.f, n1b = 0.f;

#define PROC(GG, S0, S1, N0, N1)                                                   \
    {                                                                              \
        uint4 uu = ea4q[((size_t)(GG) << 6) + lane];                               \
        int4 sv = *(const int4*)(src_csr + 4 * (GG));                              \
        int jb = 4 * (GG);                                                         \
        float m0 = (jb     >= start && jb     < end) ? 1.f : 0.f;                  \
        float m1 = (jb + 1 >= start && jb + 1 < end) ? 1.f : 0.f;                  \
        float m2 = (jb + 2 >= start && jb + 2 < end) ? 1.f : 0.f;                  \
        float m3 = (jb + 3 >= start && jb + 3 < end) ? 1.f : 0.f;                  \
        unsigned ha = hp[(size_t)sv.x * 64 + lane];                                \
        unsigned hb = hp[(size_t)sv.y * 64 + lane];                                \
        unsigned hc = hp[(size_t)sv.z * 64 + lane];                                \
        unsigned hd = hp[(size_t)sv.w * 64 + lane];                                \
        updm(__uint_as_float(ha << 16), __uint_as_float(uu.x << 16), tt, m0, S0, N0); \
        updm(__uint_as_float(ha & 0xffff0000u), __uint_as_float(uu.x & 0xffff0000u), tt, m0, S1, N1); \
        updm(__uint_as_float(hb << 16), __uint_as_float(uu.y << 16), tt, m1, S0, N0); \
        updm(__uint_as_float(hb & 0xffff0000u), __uint_as_float(uu.y & 0xffff0000u), tt, m1, S1, N1); \
        updm(__uint_as_float(hc << 16), __uint_as_float(uu.z << 16), tt, m2, S0, N0); \
        updm(__uint_as_float(hc & 0xffff0000u), __uint_as_float(uu.z & 0xffff0000u), tt, m2, S1, N1); \
        updm(__uint_as_float(hd << 16), __uint_as_float(uu.w << 16), tt, m3, S0, N0); \
        updm(__uint_as_float(hd & 0xffff0000u), __uint_as_float(uu.w & 0xffff0000u), tt, m3, S1, N1); \
    }

    int g = g0 + par;                 // this wave takes groups of its parity
    for (; g + 2 < g1; g += 4) {
        PROC(g, s0a, s1a, n0a, n1a);
        PROC(g + 2, s0b, s1b, n0b, n1b);
    }
    if (g < g1) PROC(g, s0a, s1a, n0a, n1a);
#undef PROC
    float ps0 = s0a + s0b, ps1 = s1a + s1b, pn0 = n0a + n0b, pn1 = n1a + n1b;
    part[wv][lane] = make_float4(ps0, ps1, pn0, pn1);
    __syncthreads();
    if (par == 0) {
        float4 o = part[wv + 1][lane];
        float s0 = ps0 + o.x, s1 = ps1 + o.y;
        float n0 = pn0 + o.z, n1 = pn1 + o.w;
        float2 res = ((const float2*)hres)[(size_t)node * 64 + lane];
        float ox = n0 / (s0 + 1e-16f) + res.x;
        float oy = n1 / (s1 + 1e-16f) + res.y;
        Zp[(size_t)node * 64 + lane] =
            (unsigned)(unsigned short)f2bs(ox) | ((unsigned)(unsigned short)f2bs(oy) << 16);
    }
}

// ---- fused layer MLP v6: 8-wave blocks (128 rows/block halves weight staging),
// LDS-staged weights with XOR bank swizzle, wave-private LN, single-bf16 A/z1.
// !FINAL also emits packed bf16 hp of the relu(LN) output for next layer's agg gather.
template<bool HAS_RES, bool FINAL>
__launch_bounds__(512)
__global__ void mlp_fused(const short* __restrict__ Ap,
                          const short* __restrict__ B1h, const short* __restrict__ B1l,
                          const float* __restrict__ b1, const float* __restrict__ g1,
                          const float* __restrict__ be1,
                          const short* __restrict__ B2h, const short* __restrict__ B2l,
                          const float* __restrict__ b2, const float* __restrict__ res,
                          const float* __restrict__ g2, const float* __restrict__ be2,
                          short* __restrict__ z1h,
                          float* __restrict__ Hout, float* __restrict__ HinOut,
                          unsigned* __restrict__ HP,
                          short* __restrict__ Fh, short* __restrict__ Fl)
{
    __shared__ __align__(16) short lds[32768];   // 64 KB: [0:16384]=hi, [16384:]=lo
    const int wv = threadIdx.x >> 6;             // 0..7
    const int lane = threadIdx.x & 63;
    const int l15 = lane & 15, quad = lane >> 4;
    const int tile = blockIdx.x * 8 + wv;
    const bool valid = (tile < NROWT);
    const int row = tile * 16 + l15;

    // ---- phase 1: K=128, N=256 in two 128-col halves; A single bf16 ----
    floatx4 acc[16];
#pragma unroll
    for (int t = 0; t < 16; t++) acc[t] = {0.f, 0.f, 0.f, 0.f};
    for (int hf = 0; hf < 2; hf++) {
        __syncthreads();
        {
            const float4* s1p = (const float4*)(B1h + hf * 16384);
            const float4* s2p = (const float4*)(B1l + hf * 16384);
            float4* d = (float4*)lds;
#pragma unroll
            for (int i = 0; i < 4; i++) {
                int t8 = threadIdx.x + 512 * i;                  // 0..2047
                int col = t8 >> 4, k8 = t8 & 15;
                int unit = col * 16 + (k8 ^ (col & 15));
                d[unit] = s1p[t8];
                d[2048 + unit] = s2p[t8];
            }
        }
        __syncthreads();
        if (valid) {
#pragma unroll
            for (int k0 = 0; k0 < 128; k0 += 32) {
                const int kb = k0 + quad * 8;
                const int kb8 = kb >> 3;
                short8 ah = *(const short8*)(Ap + (size_t)row * 128 + kb);
#pragma unroll
                for (int t = 0; t < 8; t++) {
                    int col = t * 16 + l15;
                    int unit = col * 16 + (kb8 ^ (col & 15));
                    const short* bp = lds + unit * 8;
                    short8 bh = *(const short8*)bp;
                    short8 bl = *(const short8*)(bp + 16384);
                    int ti = hf * 8 + t;
                    acc[ti] = __builtin_amdgcn_mfma_f32_16x16x32_bf16(ah, bh, acc[ti], 0, 0, 0);
                    acc[ti] = __builtin_amdgcn_mfma_f32_16x16x32_bf16(ah, bl, acc[ti], 0, 0, 0);
                }
            }
        }
    }
    // ---- LN1 (wave-private: wave owns full 256-col rows) ----
    if (valid) {
#pragma unroll
        for (int t = 0; t < 16; t++) {
            float bv = b1[t * 16 + l15];
#pragma unroll
            for (int r = 0; r < 4; r++) acc[t][r] += bv;
        }
        float s1[4] = {0.f, 0.f, 0.f, 0.f}, s2[4] = {0.f, 0.f, 0.f, 0.f};
#pragma unroll
        for (int t = 0; t < 16; t++)
#pragma unroll
            for (int r = 0; r < 4; r++) { s1[r] += acc[t][r]; s2[r] += acc[t][r] * acc[t][r]; }
#pragma unroll
        for (int m = 1; m <= 8; m <<= 1)
#pragma unroll
            for (int r = 0; r < 4; r++) {
                s1[r] += __shfl_xor(s1[r], m, 64);
                s2[r] += __shfl_xor(s2[r], m, 64);
            }
        float mean[4], rstd[4];
#pragma unroll
        for (int r = 0; r < 4; r++) {
            mean[r] = s1[r] * (1.f / 256.f);
            float var = s2[r] * (1.f / 256.f) - mean[r] * mean[r];
            rstd[r] = rsqrtf(var + 1e-5f);
        }
#pragma unroll
        for (int t = 0; t < 16; t++) {
            int col = t * 16 + l15;
            float gg = g1[col], bb = be1[col];
#pragma unroll
            for (int r = 0; r < 4; r++) {
                float y = fmaxf((acc[t][r] - mean[r]) * rstd[r] * gg + bb, 0.f);
                int ro = tile * 16 + quad * 4 + r;
                z1h[(size_t)ro * 256 + col] = f2bs(y);
            }
        }
    }
    // ---- phase 2: K=256, N=128 in two 64-col halves; A (z1, single bf16) from global ----
    floatx4 acc2[8];
#pragma unroll
    for (int t = 0; t < 8; t++) acc2[t] = {0.f, 0.f, 0.f, 0.f};
    for (int hf = 0; hf < 2; hf++) {
        __syncthreads();
        {
            const float4* s1p = (const float4*)(B2h + hf * 16384);
            const float4* s2p = (const float4*)(B2l + hf * 16384);
            float4* d = (float4*)lds;
#pragma unroll
            for (int i = 0; i < 4; i++) {
                int t8 = threadIdx.x + 512 * i;                  // 0..2047
                int col = t8 >> 5, k8 = t8 & 31;
                int unit = col * 32 + (k8 ^ (col & 15));
                d[unit] = s1p[t8];
                d[2048 + unit] = s2p[t8];
            }
        }
        __syncthreads();
        if (valid) {
#pragma unroll
            for (int k0 = 0; k0 < 256; k0 += 32) {
                const int kb = k0 + quad * 8;
                const int kb8 = kb >> 3;
                short8 zh = *(const short8*)(z1h + (size_t)row * 256 + kb);
#pragma unroll
                for (int t = 0; t < 4; t++) {
                    int col = t * 16 + l15;
                    int unit = col * 32 + (kb8 ^ (col & 15));
                    const short* bp = lds + unit * 8;
                    short8 bh = *(const short8*)bp;
                    short8 bl = *(const short8*)(bp + 16384);
                    int ti = hf * 4 + t;
                    acc2[ti] = __builtin_amdgcn_mfma_f32_16x16x32_bf16(zh, bh, acc2[ti], 0, 0, 0);
                    acc2[ti] = __builtin_amdgcn_mfma_f32_16x16x32_bf16(zh, bl, acc2[ti], 0, 0, 0);
                }
            }
        }
    }
    // ---- LN2 (wave-private, 128 cols) + outputs ----
    if (valid) {
#pragma unroll
        for (int t = 0; t < 8; t++) {
            int col = t * 16 + l15;
            float bv = b2[col];
#pragma unroll
            for (int r = 0; r < 4; r++) {
                acc2[t][r] += bv;
                if (HAS_RES) {
                    int ro = tile * 16 + quad * 4 + r;
                    acc2[t][r] += res[(size_t)ro * 128 + col];
                }
            }
        }
        float s1[4] = {0.f, 0.f, 0.f, 0.f}, s2[4] = {0.f, 0.f, 0.f, 0.f};
#pragma unroll
        for (int t = 0; t < 8; t++)
#pragma unroll
            for (int r = 0; r < 4; r++) { s1[r] += acc2[t][r]; s2[r] += acc2[t][r] * acc2[t][r]; }
#pragma unroll
        for (int m = 1; m <= 8; m <<= 1)
#pragma unroll
            for (int r = 0; r < 4; r++) {
                s1[r] += __shfl_xor(s1[r], m, 64);
                s2[r] += __shfl_xor(s2[r], m, 64);
            }
        float mean[4], rstd[4];
#pragma unroll
        for (int r = 0; r < 4; r++) {
            mean[r] = s1[r] * (1.f / 128.f);
            float var = s2[r] * (1.f / 128.f) - mean[r] * mean[r];
            rstd[r] = rsqrtf(var + 1e-5f);
        }
#pragma unroll
        for (int t = 0; t < 8; t++) {
            int col = t * 16 + l15;
            float gg = g2[col], bb = be2[col];
#pragma unroll
            for (int r = 0; r < 4; r++) {
                int ro = tile * 16 + quad * 4 + r;
                float x = acc2[t][r];
                float y = fmaxf((x - mean[r]) * rstd[r] * gg + bb, 0.f);
                if (FINAL) {
                    short2 sp = split_bf16(y);
                    Fh[(size_t)ro * 128 + col] = sp.x;
                    Fl[(size_t)ro * 128 + col] = sp.y;
                } else {
                    Hout[(size_t)ro * 128 + col] = x;
                    HinOut[(size_t)ro * 128 + col] = y;
                    int yb = (int)(unsigned short)f2bs(y);
                    int ob = __shfl_xor(yb, 1, 64);
                    if ((l15 & 1) == 0)
                        HP[(size_t)ro * 64 + t * 8 + (l15 >> 1)] =
                            (unsigned)yb | ((unsigned)ob << 16);
                }
            }
        }
    }
}

extern "C" void kernel_launch(void* const* d_in, const int* in_sizes, int n_in,
                              void* d_out, int out_size, void* d_ws, size_t ws_size,
                              hipStream_t stream)
{
    const float* x         = (const float*)d_in[0];
    const float* edge_attr = (const float*)d_in[1];
    const float* nw        = (const float*)d_in[2];
    const float* nb        = (const float*)d_in[3];
    const float* ew        = (const float*)d_in[4];
    const float* eb        = (const float*)d_in[5];
    const float* m1w       = (const float*)d_in[6];
    const float* m1b       = (const float*)d_in[7];
    const float* lng       = (const float*)d_in[8];
    const float* lnb       = (const float*)d_in[9];
    const float* m2w       = (const float*)d_in[10];
    const float* m2b       = (const float*)d_in[11];
    const float* tpr       = (const float*)d_in[12];
    const float* ng        = (const float*)d_in[13];
    const float* nbb       = (const float*)d_in[14];
    const float* lw        = (const float*)d_in[15];
    const float* lb        = (const float*)d_in[16];
    const int* ei  = (const int*)d_in[17];
    const int* src = ei;
    const int* dst = ei + NE;

    // ---- workspace carve (~215 MB) ----
    char* w = (char*)d_ws;
    unsigned* ea4 = (unsigned*)w; w += (size_t)NE * 128 * 2;                  // 122.88 MB
    int* src_csr  = (int*)w; w += (size_t)NE * 4;
    int* eidx_csr = (int*)w; w += (size_t)NE * 4;
    unsigned* hp  = (unsigned*)w; w += (size_t)NN * 64 * 4;                   // 7.68 MB packed bf16
    unsigned* zp  = (unsigned*)w; w += (size_t)NN * 64 * 4;                   // 7.68 MB packed bf16
    float* h   = (float*)w; w += (size_t)NN * 128 * 4;
    float* hin = (float*)w; w += (size_t)NN * 128 * 4;
    short* fin_h  = (short*)w; w += (size_t)NN * 128 * 2;
    short* fin_l  = (short*)w; w += (size_t)NN * 128 * 2;
    short* z1s_h  = (short*)w; w += (size_t)NN * 256 * 2;
    short* ew_h = (short*)w; w += (size_t)128 * 16 * 2;
    short* ew_l = (short*)w; w += (size_t)128 * 16 * 2;
    short* nw_h = (short*)w; w += (size_t)128 * 64 * 2;
    short* nw_l = (short*)w; w += (size_t)128 * 64 * 2;
    short* m1_h = (short*)w; w += (size_t)3 * 256 * 128 * 2;
    short* m1_l = (short*)w; w += (size_t)3 * 256 * 128 * 2;
    short* m2_h = (short*)w; w += (size_t)3 * 128 * 256 * 2;
    short* m2_l = (short*)w; w += (size_t)3 * 128 * 256 * 2;
    short* lw_h = (short*)w; w += (size_t)16 * 128 * 2;
    short* lw_l = (short*)w; w += (size_t)16 * 128 * 2;
    int* count  = (int*)w;   w += (size_t)NN * 4;
    int* cursor = (int*)w;   w += (size_t)NN * 4;
    int* rowptr = (int*)w;   w += (size_t)(NN + 1) * 4;

    // ---- CSR build ----
    zero_kernel<<<(2 * NN + 255) / 256, 256, 0, stream>>>(count, 2 * NN);
    hist_kernel<<<(NE + 255) / 256, 256, 0, stream>>>(dst, count);
    scan_kernel<<<1, 1024, 0, stream>>>(count, rowptr);
    scatter_kernel<<<(NE + 255) / 256, 256, 0, stream>>>(src, dst, rowptr, cursor,
                                                         src_csr, eidx_csr);

    // ---- weight pre-split ----
    presplit_all<<<(208896 + 255) / 256, 256, 0, stream>>>(
        ew, nw, m1w, m2w, lw, ew_h, ew_l, nw_h, nw_l, m1_h, m1_l, m2_h, m2_l, lw_h, lw_l);

    // ---- edge encoder (gathered, 4-edge-interleaved output) + node encoder ----
    gemm_ea<<<NE / 32, 256, 0, stream>>>(edge_attr, eidx_csr, ew_h, ew_l, eb, ea4);
    gemm_a32<64, 128><<<(NN / 16) * 8 / 4, 256, 0, stream>>>(x, nw_h, nw_l, nb, h, hp,
                                                             (NN / 16) * 8);

    const uint4* ea4q = (const uint4*)ea4;
    const int mgrid = (NROWT + 7) / 8;   // 235 blocks, 8 row-tiles each
    for (int layer = 0; layer < 3; ++layer) {
        const float* hi = (layer == 0) ? h : hin;   // residual source (fp32)
        agg_kernel<<<NN / 2, 256, 0, stream>>>(hp, hi, ea4q, src_csr, rowptr, tpr, layer, zp);
        if (layer == 0) {
            mlp_fused<false, false><<<mgrid, 512, 0, stream>>>(
                (const short*)zp, m1_h, m1_l, m1b, lng, lnb,
                m2_h, m2_l, m2b, nullptr, ng + 128, nbb + 128,
                z1s_h, h, hin, hp, nullptr, nullptr);
        } else if (layer == 1) {
            mlp_fused<true, false><<<mgrid, 512, 0, stream>>>(
                (const short*)zp, m1_h + 32768, m1_l + 32768, m1b + 256, lng + 256, lnb + 256,
                m2_h + 32768, m2_l + 32768, m2b + 128, h, ng + 256, nbb + 256,
                z1s_h, h, hin, hp, nullptr, nullptr);
        } else {
            mlp_fused<true, true><<<mgrid, 512, 0, stream>>>(
                (const short*)zp, m1_h + 65536, m1_l + 65536, m1b + 512, lng + 512, lnb + 512,
                m2_h + 65536, m2_l + 65536, m2b + 256, h, ng, nbb,
                z1s_h, nullptr, nullptr, nullptr, fin_h, fin_l);
        }
    }
    // classifier
    gemm_s<128, 16, 1, 10><<<((NN / 16) + 3) / 4, 256, 0, stream>>>(
        fin_h, fin_l, lw_h, lw_l, lb, (float*)d_out, NN / 16);
}

// Round 16
// 478.343 us; speedup vs baseline: 1.0300x; 1.0300x over previous
//
#include <hip/hip_runtime.h>
#include <hip/hip_bf16.h>

#define NN 30000
#define NE 480000
#define NROWT 1875   // NN/16

typedef __attribute__((ext_vector_type(8))) short short8;
typedef __attribute__((ext_vector_type(4))) float floatx4;

__device__ __forceinline__ short f2bs(float f) {
    __hip_bfloat16 h = __float2bfloat16(f);
    return *reinterpret_cast<short*>(&h);
}

__device__ __forceinline__ short2 split_bf16(float f) {
    __hip_bfloat16 h = __float2bfloat16(f);          // RTNE high part
    float r = f - __bfloat162float(h);               // residual, |r| <= 2^-9 |f|
    __hip_bfloat16 l = __float2bfloat16(r);
    short2 out;
    out.x = *reinterpret_cast<short*>(&h);
    out.y = *reinterpret_cast<short*>(&l);
    return out;
}

// ---- one fused presplit of ALL weights: fp32 W[K][N] -> transposed bf16 hi/lo [Npad][K] ----
__global__ void presplit_all(const float* __restrict__ ew, const float* __restrict__ nw,
                             const float* __restrict__ m1w, const float* __restrict__ m2w,
                             const float* __restrict__ lw,
                             short* __restrict__ ew_h, short* __restrict__ ew_l,
                             short* __restrict__ nw_h, short* __restrict__ nw_l,
                             short* __restrict__ m1_h, short* __restrict__ m1_l,
                             short* __restrict__ m2_h, short* __restrict__ m2_l,
                             short* __restrict__ lw_h, short* __restrict__ lw_l)
{
    int i = blockIdx.x * 256 + threadIdx.x;
    if (i < 2048) {                       // ew [16][128] -> [128][16]
        int k = i >> 7, n = i & 127;
        short2 s = split_bf16(ew[i]);
        ew_h[n * 16 + k] = s.x; ew_l[n * 16 + k] = s.y;
    } else if (i < 10240) {               // nw [64][128] -> [128][64]
        int j = i - 2048;
        int k = j >> 7, n = j & 127;
        short2 s = split_bf16(nw[j]);
        nw_h[n * 64 + k] = s.x; nw_l[n * 64 + k] = s.y;
    } else if (i < 108544) {              // m1 3x[128][256] -> 3x[256][128]
        int j = i - 10240;
        int l = j >> 15, jj = j & 32767;
        int k = jj >> 8, n = jj & 255;
        short2 s = split_bf16(m1w[j]);
        m1_h[(size_t)l * 32768 + n * 128 + k] = s.x;
        m1_l[(size_t)l * 32768 + n * 128 + k] = s.y;
    } else if (i < 206848) {              // m2 3x[256][128] -> 3x[128][256]
        int j = i - 108544;
        int l = j >> 15, jj = j & 32767;
        int k = jj >> 7, n = jj & 127;
        short2 s = split_bf16(m2w[j]);
        m2_h[(size_t)l * 32768 + n * 256 + k] = s.x;
        m2_l[(size_t)l * 32768 + n * 256 + k] = s.y;
    } else if (i < 208896) {              // lw [128][10] -> [16][128] (rows>=10 zero)
        int j = i - 206848;
        int k = j >> 4, n = j & 15;
        short2 s = (n < 10) ? split_bf16(lw[k * 10 + n]) : short2{0, 0};
        lw_h[n * 128 + k] = s.x; lw_l[n * 128 + k] = s.y;
    }
}

// ---- node encoder GEMM (A fp32, split in-kernel). One 16x16 tile/wave.
// Also emits packed bf16 pair view hp[node][64] u32 for agg gathers.
template<int K, int N>
__launch_bounds__(256)
__global__ void gemm_a32(const float* __restrict__ A, const short* __restrict__ Bh,
                         const short* __restrict__ Bl, const float* __restrict__ bias,
                         float* __restrict__ C, unsigned* __restrict__ hp, int total_waves)
{
    int wave = ((blockIdx.x * 256) + threadIdx.x) >> 6;
    if (wave >= total_waves) return;
    constexpr int NT = N / 16;
    const int mt = wave / NT, nt = wave % NT;
    const int lane = threadIdx.x & 63;
    const int l15 = lane & 15, quad = lane >> 4;
    const int row = mt * 16 + l15;
    const int col = nt * 16 + l15;
    floatx4 acc = {0.f, 0.f, 0.f, 0.f};
#pragma unroll
    for (int k0 = 0; k0 < K; k0 += 32) {
        const int kb = k0 + quad * 8;
        short8 ah, al;
        const float* ap = A + (size_t)row * K + kb;
        floatx4 a0 = *(const floatx4*)ap;
        floatx4 a1 = *(const floatx4*)(ap + 4);
#pragma unroll
        for (int j = 0; j < 4; j++) {
            short2 s0 = split_bf16(a0[j]); ah[j] = s0.x; al[j] = s0.y;
            short2 s1 = split_bf16(a1[j]); ah[j + 4] = s1.x; al[j + 4] = s1.y;
        }
        short8 bh = *(const short8*)(Bh + (size_t)col * K + kb);
        short8 bl = *(const short8*)(Bl + (size_t)col * K + kb);
        acc = __builtin_amdgcn_mfma_f32_16x16x32_bf16(ah, bh, acc, 0, 0, 0);
        acc = __builtin_amdgcn_mfma_f32_16x16x32_bf16(al, bh, acc, 0, 0, 0);
        acc = __builtin_amdgcn_mfma_f32_16x16x32_bf16(ah, bl, acc, 0, 0, 0);
    }
    float bv = bias[col];
#pragma unroll
    for (int r = 0; r < 4; r++) {
        int ro = mt * 16 + quad * 4 + r;   // C/D: col=lane&15, row=quad*4+reg
        float v = acc[r] + bv;
        C[(size_t)ro * N + col] = v;
        int mb = (int)(unsigned short)f2bs(v);
        int ob = __shfl_xor(mb, 1, 64);
        if ((l15 & 1) == 0)
            hp[(size_t)ro * 64 + nt * 8 + (l15 >> 1)] = (unsigned)mb | ((unsigned)ob << 16);
    }
}

// ---- generic pre-split GEMM (classifier): 16 x (16*NTW) tile per wave ----
template<int K, int NTOT, int NTW, int NREAL>
__launch_bounds__(256)
__global__ void gemm_s(const short* __restrict__ Ah, const short* __restrict__ Al,
                       const short* __restrict__ Bh, const short* __restrict__ Bl,
                       const float* __restrict__ bias, float* __restrict__ C, int total_waves)
{
    int wave = ((blockIdx.x * 256) + threadIdx.x) >> 6;
    if (wave >= total_waves) return;
    constexpr int NG = NTOT / (16 * NTW);
    const int mt = wave / NG, g = wave % NG;
    const int lane = threadIdx.x & 63;
    const int l15 = lane & 15, quad = lane >> 4;
    const int row = mt * 16 + l15;
    floatx4 acc[NTW];
#pragma unroll
    for (int t = 0; t < NTW; t++) acc[t] = {0.f, 0.f, 0.f, 0.f};
#pragma unroll
    for (int k0 = 0; k0 < K; k0 += 32) {
        const int kb = k0 + quad * 8;
        short8 ah = *(const short8*)(Ah + (size_t)row * K + kb);
        short8 al = *(const short8*)(Al + (size_t)row * K + kb);
#pragma unroll
        for (int t = 0; t < NTW; t++) {
            int col = g * NTW * 16 + t * 16 + l15;
            short8 bh = *(const short8*)(Bh + (size_t)col * K + kb);
            short8 bl = *(const short8*)(Bl + (size_t)col * K + kb);
            acc[t] = __builtin_amdgcn_mfma_f32_16x16x32_bf16(ah, bh, acc[t], 0, 0, 0);
            acc[t] = __builtin_amdgcn_mfma_f32_16x16x32_bf16(al, bh, acc[t], 0, 0, 0);
            acc[t] = __builtin_amdgcn_mfma_f32_16x16x32_bf16(ah, bl, acc[t], 0, 0, 0);
        }
    }
#pragma unroll
    for (int t = 0; t < NTW; t++) {
        int col = g * NTW * 16 + t * 16 + l15;
        if (col < NREAL) {
            float bv = bias[col];
#pragma unroll
            for (int r = 0; r < 4; r++) {
                int ro = mt * 16 + quad * 4 + r;
                C[(size_t)ro * NREAL + col] = acc[t][r] + bv;
            }
        }
    }
}

// ---- edge-encoder GEMM: gathers attr via eidx, writes 4-edge-interleaved ea4 layout ----
__launch_bounds__(256)
__global__ void gemm_ea(const float* __restrict__ edge_attr, const int* __restrict__ eidx_csr,
                        const short* __restrict__ Bh, const short* __restrict__ Bl,
                        const float* __restrict__ bias, unsigned* __restrict__ ea4)
{
    __shared__ short tile[2][16][132];
    const int wv = threadIdx.x >> 6;
    const int sub = wv >> 1, g = wv & 1;
    const int lane = threadIdx.x & 63;
    const int l15 = lane & 15, quad = lane >> 4;
    const int p = blockIdx.x * 32 + sub * 16 + l15;
    short8 a;
    if (quad < 2) {
        int e = eidx_csr[p];
        const float* ap = edge_attr + (size_t)e * 16 + quad * 8;
        floatx4 a0 = *(const floatx4*)ap;
        floatx4 a1 = *(const floatx4*)(ap + 4);
#pragma unroll
        for (int j = 0; j < 4; j++) { a[j] = f2bs(a0[j]); a[j + 4] = f2bs(a1[j]); }
    } else {
#pragma unroll
        for (int j = 0; j < 8; j++) a[j] = 0;
    }
    floatx4 acc[4];
#pragma unroll
    for (int t = 0; t < 4; t++) acc[t] = {0.f, 0.f, 0.f, 0.f};
#pragma unroll
    for (int t = 0; t < 4; t++) {
        int col = g * 64 + t * 16 + l15;
        short8 bh, bl;
        if (quad < 2) {
            bh = *(const short8*)(Bh + (size_t)col * 16 + quad * 8);
            bl = *(const short8*)(Bl + (size_t)col * 16 + quad * 8);
        } else {
#pragma unroll
            for (int j = 0; j < 8; j++) { bh[j] = 0; bl[j] = 0; }
        }
        acc[t] = __builtin_amdgcn_mfma_f32_16x16x32_bf16(a, bh, acc[t], 0, 0, 0);
        acc[t] = __builtin_amdgcn_mfma_f32_16x16x32_bf16(a, bl, acc[t], 0, 0, 0);
    }
#pragma unroll
    for (int t = 0; t < 4; t++) {
        int col = g * 64 + t * 16 + l15;
        float bv = bias[col];
#pragma unroll
        for (int r = 0; r < 4; r++)
            tile[sub][quad * 4 + r][col] = f2bs(acc[t][r] + bv);
    }
    __syncthreads();
#pragma unroll
    for (int c = 0; c < 2; c++) {
        int idx = threadIdx.x + 256 * c;          // 0..511
        int o = idx * 16;
        int g4l = o >> 10;
        int lp = (o & 1023) >> 4;
        unsigned u[4];
#pragma unroll
        for (int e = 0; e < 4; e++) {
            int rl = g4l * 4 + e;
            u[e] = *(const unsigned*)&tile[rl >> 4][rl & 15][2 * lp];
        }
        uint4 val = make_uint4(u[0], u[1], u[2], u[3]);
        *(uint4*)((char*)ea4 + (size_t)blockIdx.x * 8192 + o) = val;
    }
}

// ---- zero fill ----
__global__ void zero_kernel(int* __restrict__ p, int n)
{
    int i = blockIdx.x * 256 + threadIdx.x;
    if (i < n) p[i] = 0;
}

// ---- CSR build ----
__global__ void hist_kernel(const int* __restrict__ dst, int* __restrict__ count)
{
    int e = blockIdx.x * 256 + threadIdx.x;
    if (e < NE) atomicAdd(count + dst[e], 1);
}

__launch_bounds__(1024)
__global__ void scan_kernel(const int* __restrict__ count, int* __restrict__ rowptr)
{
    __shared__ int part[1024];
    const int t = threadIdx.x;
    const int CH = (NN + 1023) / 1024;          // 30
    const int base = t * CH;
    int sum = 0;
    for (int j = 0; j < CH; j++) {
        int idx = base + j;
        if (idx < NN) sum += count[idx];
    }
    part[t] = sum;
    __syncthreads();
    for (int d = 1; d < 1024; d <<= 1) {
        int v = (t >= d) ? part[t - d] : 0;
        __syncthreads();
        part[t] += v;
        __syncthreads();
    }
    int off = (t == 0) ? 0 : part[t - 1];
    for (int j = 0; j < CH; j++) {
        int idx = base + j;
        if (idx < NN) { rowptr[idx] = off; off += count[idx]; }
    }
    if (t == 1023) rowptr[NN] = part[1023];
}

__global__ void scatter_kernel(const int* __restrict__ src, const int* __restrict__ dst,
                               const int* __restrict__ rowptr, int* __restrict__ cursor,
                               int* __restrict__ src_csr, int* __restrict__ eidx_csr)
{
    int e = blockIdx.x * 256 + threadIdx.x;
    if (e >= NE) return;
    int d = dst[e];
    int pos = rowptr[d] + atomicAdd(cursor + d, 1);
    src_csr[pos] = src[e];
    eidx_csr[pos] = e;
}

// ---- fused aggregation v4: bf16 hp gather, masked 4-edge groups, 2 waves per node ----
__device__ __forceinline__ void updm(float hv, float av, float tt, float m,
                                     float& s, float& n)
{
    float g = fmaxf(hv + av, 0.f) + 1e-7f;   // msg
    float e = __expf(g * tt) * m;             // exp(logit), masked
    s += e;
    n = fmaf(g, e, n);
}

__launch_bounds__(256)
__global__ void agg_kernel(const unsigned* __restrict__ hp, const float* __restrict__ hres,
                           const uint4* __restrict__ ea4q, const int* __restrict__ src_csr,
                           const int* __restrict__ rowptr, const float* __restrict__ tptr,
                           int layer, unsigned* __restrict__ Zp)
{
    __shared__ float4 part[4][64];
    const int wv = threadIdx.x >> 6;
    const int node = blockIdx.x * 2 + (wv >> 1);   // grid = NN/2 exact
    const int par = wv & 1;
    const int lane = threadIdx.x & 63;
    const float tt = tptr[layer];
    const int start = rowptr[node];
    const int end = rowptr[node + 1];
    const int g0 = start >> 2, g1 = (end + 3) >> 2;
    float s0a = 0.f, s1a = 0.f, n0a = 0.f, n1a = 0.f;
    float s0b = 0.f, s1b = 0.f, n0b = 0.f, n1b = 0.f;

#define PROC(GG, S0, S1, N0, N1)                                                   \
    {                                                                              \
        uint4 uu = ea4q[((size_t)(GG) << 6) + lane];                               \
        int4 sv = *(const int4*)(src_csr + 4 * (GG));                              \
        int jb = 4 * (GG);                                                         \
        float m0 = (jb     >= start && jb     < end) ? 1.f : 0.f;                  \
        float m1 = (jb + 1 >= start && jb + 1 < end) ? 1.f : 0.f;                  \
        float m2 = (jb + 2 >= start && jb + 2 < end) ? 1.f : 0.f;                  \
        float m3 = (jb + 3 >= start && jb + 3 < end) ? 1.f : 0.f;                  \
        unsigned ha = hp[(size_t)sv.x * 64 + lane];                                \
        unsigned hb = hp[(size_t)sv.y * 64 + lane];                                \
        unsigned hc = hp[(size_t)sv.z * 64 + lane];                                \
        unsigned hd = hp[(size_t)sv.w * 64 + lane];                                \
        updm(__uint_as_float(ha << 16), __uint_as_float(uu.x << 16), tt, m0, S0, N0); \
        updm(__uint_as_float(ha & 0xffff0000u), __uint_as_float(uu.x & 0xffff0000u), tt, m0, S1, N1); \
        updm(__uint_as_float(hb << 16), __uint_as_float(uu.y << 16), tt, m1, S0, N0); \
        updm(__uint_as_float(hb & 0xffff0000u), __uint_as_float(uu.y & 0xffff0000u), tt, m1, S1, N1); \
        updm(__uint_as_float(hc << 16), __uint_as_float(uu.z << 16), tt, m2, S0, N0); \
        updm(__uint_as_float(hc & 0xffff0000u), __uint_as_float(uu.z & 0xffff0000u), tt, m2, S1, N1); \
        updm(__uint_as_float(hd << 16), __uint_as_float(uu.w << 16), tt, m3, S0, N0); \
        updm(__uint_as_float(hd & 0xffff0000u), __uint_as_float(uu.w & 0xffff0000u), tt, m3, S1, N1); \
    }

    int g = g0 + par;                 // this wave takes groups of its parity
    for (; g + 2 < g1; g += 4) {
        PROC(g, s0a, s1a, n0a, n1a);
        PROC(g + 2, s0b, s1b, n0b, n1b);
    }
    if (g < g1) PROC(g, s0a, s1a, n0a, n1a);
#undef PROC
    float ps0 = s0a + s0b, ps1 = s1a + s1b, pn0 = n0a + n0b, pn1 = n1a + n1b;
    part[wv][lane] = make_float4(ps0, ps1, pn0, pn1);
    __syncthreads();
    if (par == 0) {
        float4 o = part[wv + 1][lane];
        float s0 = ps0 + o.x, s1 = ps1 + o.y;
        float n0 = pn0 + o.z, n1 = pn1 + o.w;
        float2 res = ((const float2*)hres)[(size_t)node * 64 + lane];
        float ox = n0 / (s0 + 1e-16f) + res.x;
        float oy = n1 / (s1 + 1e-16f) + res.y;
        Zp[(size_t)node * 64 + lane] =
            (unsigned)(unsigned short)f2bs(ox) | ((unsigned)(unsigned short)f2bs(oy) << 16);
    }
}

// ---- fused layer MLP v5: 256 threads, 4 row-tiles/block (469 blocks — full subscription),
// LDS-staged weights with XOR bank swizzle, wave-private LN, single-bf16 A/z1.
// !FINAL also emits packed bf16 hp of the relu(LN) output for next layer's agg gather.
template<bool HAS_RES, bool FINAL>
__launch_bounds__(256)
__global__ void mlp_fused(const short* __restrict__ Ap,
                          const short* __restrict__ B1h, const short* __restrict__ B1l,
                          const float* __restrict__ b1, const float* __restrict__ g1,
                          const float* __restrict__ be1,
                          const short* __restrict__ B2h, const short* __restrict__ B2l,
                          const float* __restrict__ b2, const float* __restrict__ res,
                          const float* __restrict__ g2, const float* __restrict__ be2,
                          short* __restrict__ z1h,
                          float* __restrict__ Hout, float* __restrict__ HinOut,
                          unsigned* __restrict__ HP,
                          short* __restrict__ Fh, short* __restrict__ Fl)
{
    __shared__ __align__(16) short lds[32768];   // 64 KB: [0:16384]=hi, [16384:]=lo
    const int wv = threadIdx.x >> 6;
    const int lane = threadIdx.x & 63;
    const int l15 = lane & 15, quad = lane >> 4;
    const int tile = blockIdx.x * 4 + wv;
    const bool valid = (tile < NROWT);
    const int row = tile * 16 + l15;

    // ---- phase 1: K=128, N=256 in two 128-col halves; A single bf16 ----
    floatx4 acc[16];
#pragma unroll
    for (int t = 0; t < 16; t++) acc[t] = {0.f, 0.f, 0.f, 0.f};
    for (int hf = 0; hf < 2; hf++) {
        __syncthreads();
        {
            const float4* s1p = (const float4*)(B1h + hf * 16384);
            const float4* s2p = (const float4*)(B1l + hf * 16384);
            float4* d = (float4*)lds;
#pragma unroll
            for (int i = 0; i < 8; i++) {
                int t8 = threadIdx.x + 256 * i;                  // 0..2047
                int col = t8 >> 4, k8 = t8 & 15;
                int unit = col * 16 + (k8 ^ (col & 15));
                d[unit] = s1p[t8];
                d[2048 + unit] = s2p[t8];
            }
        }
        __syncthreads();
        if (valid) {
#pragma unroll
            for (int k0 = 0; k0 < 128; k0 += 32) {
                const int kb = k0 + quad * 8;
                const int kb8 = kb >> 3;
                short8 ah = *(const short8*)(Ap + (size_t)row * 128 + kb);
#pragma unroll
                for (int t = 0; t < 8; t++) {
                    int col = t * 16 + l15;
                    int unit = col * 16 + (kb8 ^ (col & 15));
                    const short* bp = lds + unit * 8;
                    short8 bh = *(const short8*)bp;
                    short8 bl = *(const short8*)(bp + 16384);
                    int ti = hf * 8 + t;
                    acc[ti] = __builtin_amdgcn_mfma_f32_16x16x32_bf16(ah, bh, acc[ti], 0, 0, 0);
                    acc[ti] = __builtin_amdgcn_mfma_f32_16x16x32_bf16(ah, bl, acc[ti], 0, 0, 0);
                }
            }
        }
    }
    // ---- LN1 (wave-private: wave owns full 256-col rows) ----
    if (valid) {
#pragma unroll
        for (int t = 0; t < 16; t++) {
            float bv = b1[t * 16 + l15];
#pragma unroll
            for (int r = 0; r < 4; r++) acc[t][r] += bv;
        }
        float s1[4] = {0.f, 0.f, 0.f, 0.f}, s2[4] = {0.f, 0.f, 0.f, 0.f};
#pragma unroll
        for (int t = 0; t < 16; t++)
#pragma unroll
            for (int r = 0; r < 4; r++) { s1[r] += acc[t][r]; s2[r] += acc[t][r] * acc[t][r]; }
#pragma unroll
        for (int m = 1; m <= 8; m <<= 1)
#pragma unroll
            for (int r = 0; r < 4; r++) {
                s1[r] += __shfl_xor(s1[r], m, 64);
                s2[r] += __shfl_xor(s2[r], m, 64);
            }
        float mean[4], rstd[4];
#pragma unroll
        for (int r = 0; r < 4; r++) {
            mean[r] = s1[r] * (1.f / 256.f);
            float var = s2[r] * (1.f / 256.f) - mean[r] * mean[r];
            rstd[r] = rsqrtf(var + 1e-5f);
        }
#pragma unroll
        for (int t = 0; t < 16; t++) {
            int col = t * 16 + l15;
            float gg = g1[col], bb = be1[col];
#pragma unroll
            for (int r = 0; r < 4; r++) {
                float y = fmaxf((acc[t][r] - mean[r]) * rstd[r] * gg + bb, 0.f);
                int ro = tile * 16 + quad * 4 + r;
                z1h[(size_t)ro * 256 + col] = f2bs(y);
            }
        }
    }
    // ---- phase 2: K=256, N=128 in two 64-col halves; A (z1, single bf16) from global ----
    floatx4 acc2[8];
#pragma unroll
    for (int t = 0; t < 8; t++) acc2[t] = {0.f, 0.f, 0.f, 0.f};
    for (int hf = 0; hf < 2; hf++) {
        __syncthreads();
        {
            const float4* s1p = (const float4*)(B2h + hf * 16384);
            const float4* s2p = (const float4*)(B2l + hf * 16384);
            float4* d = (float4*)lds;
#pragma unroll
            for (int i = 0; i < 8; i++) {
                int t8 = threadIdx.x + 256 * i;                  // 0..2047
                int col = t8 >> 5, k8 = t8 & 31;
                int unit = col * 32 + (k8 ^ (col & 15));
                d[unit] = s1p[t8];
                d[2048 + unit] = s2p[t8];
            }
        }
        __syncthreads();
        if (valid) {
#pragma unroll
            for (int k0 = 0; k0 < 256; k0 += 32) {
                const int kb = k0 + quad * 8;
                const int kb8 = kb >> 3;
                short8 zh = *(const short8*)(z1h + (size_t)row * 256 + kb);
#pragma unroll
                for (int t = 0; t < 4; t++) {
                    int col = t * 16 + l15;
                    int unit = col * 32 + (kb8 ^ (col & 15));
                    const short* bp = lds + unit * 8;
                    short8 bh = *(const short8*)bp;
                    short8 bl = *(const short8*)(bp + 16384);
                    int ti = hf * 4 + t;
                    acc2[ti] = __builtin_amdgcn_mfma_f32_16x16x32_bf16(zh, bh, acc2[ti], 0, 0, 0);
                    acc2[ti] = __builtin_amdgcn_mfma_f32_16x16x32_bf16(zh, bl, acc2[ti], 0, 0, 0);
                }
            }
        }
    }
    // ---- LN2 (wave-private, 128 cols) + outputs ----
    if (valid) {
#pragma unroll
        for (int t = 0; t < 8; t++) {
            int col = t * 16 + l15;
            float bv = b2[col];
#pragma unroll
            for (int r = 0; r < 4; r++) {
                acc2[t][r] += bv;
                if (HAS_RES) {
                    int ro = tile * 16 + quad * 4 + r;
                    acc2[t][r] += res[(size_t)ro * 128 + col];
                }
            }
        }
        float s1[4] = {0.f, 0.f, 0.f, 0.f}, s2[4] = {0.f, 0.f, 0.f, 0.f};
#pragma unroll
        for (int t = 0; t < 8; t++)
#pragma unroll
            for (int r = 0; r < 4; r++) { s1[r] += acc2[t][r]; s2[r] += acc2[t][r] * acc2[t][r]; }
#pragma unroll
        for (int m = 1; m <= 8; m <<= 1)
#pragma unroll
            for (int r = 0; r < 4; r++) {
                s1[r] += __shfl_xor(s1[r], m, 64);
                s2[r] += __shfl_xor(s2[r], m, 64);
            }
        float mean[4], rstd[4];
#pragma unroll
        for (int r = 0; r < 4; r++) {
            mean[r] = s1[r] * (1.f / 128.f);
            float var = s2[r] * (1.f / 128.f) - mean[r] * mean[r];
            rstd[r] = rsqrtf(var + 1e-5f);
        }
#pragma unroll
        for (int t = 0; t < 8; t++) {
            int col = t * 16 + l15;
            float gg = g2[col], bb = be2[col];
#pragma unroll
            for (int r = 0; r < 4; r++) {
                int ro = tile * 16 + quad * 4 + r;
                float x = acc2[t][r];
                float y = fmaxf((x - mean[r]) * rstd[r] * gg + bb, 0.f);
                if (FINAL) {
                    short2 sp = split_bf16(y);
                    Fh[(size_t)ro * 128 + col] = sp.x;
                    Fl[(size_t)ro * 128 + col] = sp.y;
                } else {
                    Hout[(size_t)ro * 128 + col] = x;
                    HinOut[(size_t)ro * 128 + col] = y;
                    int yb = (int)(unsigned short)f2bs(y);
                    int ob = __shfl_xor(yb, 1, 64);
                    if ((l15 & 1) == 0)
                        HP[(size_t)ro * 64 + t * 8 + (l15 >> 1)] =
                            (unsigned)yb | ((unsigned)ob << 16);
                }
            }
        }
    }
}

extern "C" void kernel_launch(void* const* d_in, const int* in_sizes, int n_in,
                              void* d_out, int out_size, void* d_ws, size_t ws_size,
                              hipStream_t stream)
{
    const float* x         = (const float*)d_in[0];
    const float* edge_attr = (const float*)d_in[1];
    const float* nw        = (const float*)d_in[2];
    const float* nb        = (const float*)d_in[3];
    const float* ew        = (const float*)d_in[4];
    const float* eb        = (const float*)d_in[5];
    const float* m1w       = (const float*)d_in[6];
    const float* m1b       = (const float*)d_in[7];
    const float* lng       = (const float*)d_in[8];
    const float* lnb       = (const float*)d_in[9];
    const float* m2w       = (const float*)d_in[10];
    const float* m2b       = (const float*)d_in[11];
    const float* tpr       = (const float*)d_in[12];
    const float* ng        = (const float*)d_in[13];
    const float* nbb       = (const float*)d_in[14];
    const float* lw        = (const float*)d_in[15];
    const float* lb        = (const float*)d_in[16];
    const int* ei  = (const int*)d_in[17];
    const int* src = ei;
    const int* dst = ei + NE;

    // ---- workspace carve (~215 MB) ----
    char* w = (char*)d_ws;
    unsigned* ea4 = (unsigned*)w; w += (size_t)NE * 128 * 2;                  // 122.88 MB
    int* src_csr  = (int*)w; w += (size_t)NE * 4;
    int* eidx_csr = (int*)w; w += (size_t)NE * 4;
    unsigned* hp  = (unsigned*)w; w += (size_t)NN * 64 * 4;                   // 7.68 MB packed bf16
    unsigned* zp  = (unsigned*)w; w += (size_t)NN * 64 * 4;                   // 7.68 MB packed bf16
    float* h   = (float*)w; w += (size_t)NN * 128 * 4;
    float* hin = (float*)w; w += (size_t)NN * 128 * 4;
    short* fin_h  = (short*)w; w += (size_t)NN * 128 * 2;
    short* fin_l  = (short*)w; w += (size_t)NN * 128 * 2;
    short* z1s_h  = (short*)w; w += (size_t)NN * 256 * 2;
    short* ew_h = (short*)w; w += (size_t)128 * 16 * 2;
    short* ew_l = (short*)w; w += (size_t)128 * 16 * 2;
    short* nw_h = (short*)w; w += (size_t)128 * 64 * 2;
    short* nw_l = (short*)w; w += (size_t)128 * 64 * 2;
    short* m1_h = (short*)w; w += (size_t)3 * 256 * 128 * 2;
    short* m1_l = (short*)w; w += (size_t)3 * 256 * 128 * 2;
    short* m2_h = (short*)w; w += (size_t)3 * 128 * 256 * 2;
    short* m2_l = (short*)w; w += (size_t)3 * 128 * 256 * 2;
    short* lw_h = (short*)w; w += (size_t)16 * 128 * 2;
    short* lw_l = (short*)w; w += (size_t)16 * 128 * 2;
    int* count  = (int*)w;   w += (size_t)NN * 4;
    int* cursor = (int*)w;   w += (size_t)NN * 4;
    int* rowptr = (int*)w;   w += (size_t)(NN + 1) * 4;

    // ---- CSR build ----
    zero_kernel<<<(2 * NN + 255) / 256, 256, 0, stream>>>(count, 2 * NN);
    hist_kernel<<<(NE + 255) / 256, 256, 0, stream>>>(dst, count);
    scan_kernel<<<1, 1024, 0, stream>>>(count, rowptr);
    scatter_kernel<<<(NE + 255) / 256, 256, 0, stream>>>(src, dst, rowptr, cursor,
                                                         src_csr, eidx_csr);

    // ---- weight pre-split ----
    presplit_all<<<(208896 + 255) / 256, 256, 0, stream>>>(
        ew, nw, m1w, m2w, lw, ew_h, ew_l, nw_h, nw_l, m1_h, m1_l, m2_h, m2_l, lw_h, lw_l);

    // ---- edge encoder (gathered, 4-edge-interleaved output) + node encoder ----
    gemm_ea<<<NE / 32, 256, 0, stream>>>(edge_attr, eidx_csr, ew_h, ew_l, eb, ea4);
    gemm_a32<64, 128><<<(NN / 16) * 8 / 4, 256, 0, stream>>>(x, nw_h, nw_l, nb, h, hp,
                                                             (NN / 16) * 8);

    const uint4* ea4q = (const uint4*)ea4;
    const int mgrid = (NROWT + 3) / 4;   // 469 blocks, 4 row-tiles each
    for (int layer = 0; layer < 3; ++layer) {
        const float* hi = (layer == 0) ? h : hin;   // residual source (fp32)
        agg_kernel<<<NN / 2, 256, 0, stream>>>(hp, hi, ea4q, src_csr, rowptr, tpr, layer, zp);
        if (layer == 0) {
            mlp_fused<false, false><<<mgrid, 256, 0, stream>>>(
                (const short*)zp, m1_h, m1_l, m1b, lng, lnb,
                m2_h, m2_l, m2b, nullptr, ng + 128, nbb + 128,
                z1s_h, h, hin, hp, nullptr, nullptr);
        } else if (layer == 1) {
            mlp_fused<true, false><<<mgrid, 256, 0, stream>>>(
                (const short*)zp, m1_h + 32768, m1_l + 32768, m1b + 256, lng + 256, lnb + 256,
                m2_h + 32768, m2_l + 32768, m2b + 128, h, ng + 256, nbb + 256,
                z1s_h, h, hin, hp, nullptr, nullptr);
        } else {
            mlp_fused<true, true><<<mgrid, 256, 0, stream>>>(
                (const short*)zp, m1_h + 65536, m1_l + 65536, m1b + 512, lng + 512, lnb + 512,
                m2_h + 65536, m2_l + 65536, m2b + 256, h, ng, nbb,
                z1s_h, nullptr, nullptr, nullptr, fin_h, fin_l);
        }
    }
    // classifier
    gemm_s<128, 16, 1, 10><<<((NN / 16) + 3) / 4, 256, 0, stream>>>(
        fin_h, fin_l, lw_h, lw_l, lb, (float*)d_out, NN / 16);
}

// Round 17
// 455.144 us; speedup vs baseline: 1.0825x; 1.0510x over previous
//
#include <hip/hip_runtime.h>
#include <hip/hip_bf16.h>

#define NN 30000
#define NE 480000
#define NROWT 1875   // NN/16

typedef __attribute__((ext_vector_type(8))) short short8;
typedef __attribute__((ext_vector_type(4))) float floatx4;

__device__ __forceinline__ short f2bs(float f) {
    __hip_bfloat16 h = __float2bfloat16(f);
    return *reinterpret_cast<short*>(&h);
}

__device__ __forceinline__ short2 split_bf16(float f) {
    __hip_bfloat16 h = __float2bfloat16(f);          // RTNE high part
    float r = f - __bfloat162float(h);               // residual, |r| <= 2^-9 |f|
    __hip_bfloat16 l = __float2bfloat16(r);
    short2 out;
    out.x = *reinterpret_cast<short*>(&h);
    out.y = *reinterpret_cast<short*>(&l);
    return out;
}

// ---- one fused presplit of ALL weights: fp32 W[K][N] -> transposed bf16 hi/lo [Npad][K] ----
__global__ void presplit_all(const float* __restrict__ ew, const float* __restrict__ nw,
                             const float* __restrict__ m1w, const float* __restrict__ m2w,
                             const float* __restrict__ lw,
                             short* __restrict__ ew_h, short* __restrict__ ew_l,
                             short* __restrict__ nw_h, short* __restrict__ nw_l,
                             short* __restrict__ m1_h, short* __restrict__ m1_l,
                             short* __restrict__ m2_h, short* __restrict__ m2_l,
                             short* __restrict__ lw_h, short* __restrict__ lw_l)
{
    int i = blockIdx.x * 256 + threadIdx.x;
    if (i < 2048) {                       // ew [16][128] -> [128][16]
        int k = i >> 7, n = i & 127;
        short2 s = split_bf16(ew[i]);
        ew_h[n * 16 + k] = s.x; ew_l[n * 16 + k] = s.y;
    } else if (i < 10240) {               // nw [64][128] -> [128][64]
        int j = i - 2048;
        int k = j >> 7, n = j & 127;
        short2 s = split_bf16(nw[j]);
        nw_h[n * 64 + k] = s.x; nw_l[n * 64 + k] = s.y;
    } else if (i < 108544) {              // m1 3x[128][256] -> 3x[256][128]
        int j = i - 10240;
        int l = j >> 15, jj = j & 32767;
        int k = jj >> 8, n = jj & 255;
        short2 s = split_bf16(m1w[j]);
        m1_h[(size_t)l * 32768 + n * 128 + k] = s.x;
        m1_l[(size_t)l * 32768 + n * 128 + k] = s.y;
    } else if (i < 206848) {              // m2 3x[256][128] -> 3x[128][256]
        int j = i - 108544;
        int l = j >> 15, jj = j & 32767;
        int k = jj >> 7, n = jj & 127;
        short2 s = split_bf16(m2w[j]);
        m2_h[(size_t)l * 32768 + n * 256 + k] = s.x;
        m2_l[(size_t)l * 32768 + n * 256 + k] = s.y;
    } else if (i < 208896) {              // lw [128][10] -> [16][128] (rows>=10 zero)
        int j = i - 206848;
        int k = j >> 4, n = j & 15;
        short2 s = (n < 10) ? split_bf16(lw[k * 10 + n]) : short2{0, 0};
        lw_h[n * 128 + k] = s.x; lw_l[n * 128 + k] = s.y;
    }
}

// ---- node encoder GEMM (A fp32, split in-kernel). One 16x16 tile/wave.
// Also emits packed bf16 pair view hp[node][64] u32 for agg gathers.
template<int K, int N>
__launch_bounds__(256)
__global__ void gemm_a32(const float* __restrict__ A, const short* __restrict__ Bh,
                         const short* __restrict__ Bl, const float* __restrict__ bias,
                         float* __restrict__ C, unsigned* __restrict__ hp, int total_waves)
{
    int wave = ((blockIdx.x * 256) + threadIdx.x) >> 6;
    if (wave >= total_waves) return;
    constexpr int NT = N / 16;
    const int mt = wave / NT, nt = wave % NT;
    const int lane = threadIdx.x & 63;
    const int l15 = lane & 15, quad = lane >> 4;
    const int row = mt * 16 + l15;
    const int col = nt * 16 + l15;
    floatx4 acc = {0.f, 0.f, 0.f, 0.f};
#pragma unroll
    for (int k0 = 0; k0 < K; k0 += 32) {
        const int kb = k0 + quad * 8;
        short8 ah, al;
        const float* ap = A + (size_t)row * K + kb;
        floatx4 a0 = *(const floatx4*)ap;
        floatx4 a1 = *(const floatx4*)(ap + 4);
#pragma unroll
        for (int j = 0; j < 4; j++) {
            short2 s0 = split_bf16(a0[j]); ah[j] = s0.x; al[j] = s0.y;
            short2 s1 = split_bf16(a1[j]); ah[j + 4] = s1.x; al[j + 4] = s1.y;
        }
        short8 bh = *(const short8*)(Bh + (size_t)col * K + kb);
        short8 bl = *(const short8*)(Bl + (size_t)col * K + kb);
        acc = __builtin_amdgcn_mfma_f32_16x16x32_bf16(ah, bh, acc, 0, 0, 0);
        acc = __builtin_amdgcn_mfma_f32_16x16x32_bf16(al, bh, acc, 0, 0, 0);
        acc = __builtin_amdgcn_mfma_f32_16x16x32_bf16(ah, bl, acc, 0, 0, 0);
    }
    float bv = bias[col];
#pragma unroll
    for (int r = 0; r < 4; r++) {
        int ro = mt * 16 + quad * 4 + r;   // C/D: col=lane&15, row=quad*4+reg
        float v = acc[r] + bv;
        C[(size_t)ro * N + col] = v;
        int mb = (int)(unsigned short)f2bs(v);
        int ob = __shfl_xor(mb, 1, 64);
        if ((l15 & 1) == 0)
            hp[(size_t)ro * 64 + nt * 8 + (l15 >> 1)] = (unsigned)mb | ((unsigned)ob << 16);
    }
}

// ---- edge-encoder GEMM: gathers attr via eidx, writes 4-edge-interleaved ea4 layout ----
__launch_bounds__(256)
__global__ void gemm_ea(const float* __restrict__ edge_attr, const int* __restrict__ eidx_csr,
                        const short* __restrict__ Bh, const short* __restrict__ Bl,
                        const float* __restrict__ bias, unsigned* __restrict__ ea4)
{
    __shared__ short tile[2][16][132];
    const int wv = threadIdx.x >> 6;
    const int sub = wv >> 1, g = wv & 1;
    const int lane = threadIdx.x & 63;
    const int l15 = lane & 15, quad = lane >> 4;
    const int p = blockIdx.x * 32 + sub * 16 + l15;
    short8 a;
    if (quad < 2) {
        int e = eidx_csr[p];
        const float* ap = edge_attr + (size_t)e * 16 + quad * 8;
        floatx4 a0 = *(const floatx4*)ap;
        floatx4 a1 = *(const floatx4*)(ap + 4);
#pragma unroll
        for (int j = 0; j < 4; j++) { a[j] = f2bs(a0[j]); a[j + 4] = f2bs(a1[j]); }
    } else {
#pragma unroll
        for (int j = 0; j < 8; j++) a[j] = 0;
    }
    floatx4 acc[4];
#pragma unroll
    for (int t = 0; t < 4; t++) acc[t] = {0.f, 0.f, 0.f, 0.f};
#pragma unroll
    for (int t = 0; t < 4; t++) {
        int col = g * 64 + t * 16 + l15;
        short8 bh, bl;
        if (quad < 2) {
            bh = *(const short8*)(Bh + (size_t)col * 16 + quad * 8);
            bl = *(const short8*)(Bl + (size_t)col * 16 + quad * 8);
        } else {
#pragma unroll
            for (int j = 0; j < 8; j++) { bh[j] = 0; bl[j] = 0; }
        }
        acc[t] = __builtin_amdgcn_mfma_f32_16x16x32_bf16(a, bh, acc[t], 0, 0, 0);
        acc[t] = __builtin_amdgcn_mfma_f32_16x16x32_bf16(a, bl, acc[t], 0, 0, 0);
    }
#pragma unroll
    for (int t = 0; t < 4; t++) {
        int col = g * 64 + t * 16 + l15;
        float bv = bias[col];
#pragma unroll
        for (int r = 0; r < 4; r++)
            tile[sub][quad * 4 + r][col] = f2bs(acc[t][r] + bv);
    }
    __syncthreads();
#pragma unroll
    for (int c = 0; c < 2; c++) {
        int idx = threadIdx.x + 256 * c;          // 0..511
        int o = idx * 16;
        int g4l = o >> 10;
        int lp = (o & 1023) >> 4;
        unsigned u[4];
#pragma unroll
        for (int e = 0; e < 4; e++) {
            int rl = g4l * 4 + e;
            u[e] = *(const unsigned*)&tile[rl >> 4][rl & 15][2 * lp];
        }
        uint4 val = make_uint4(u[0], u[1], u[2], u[3]);
        *(uint4*)((char*)ea4 + (size_t)blockIdx.x * 8192 + o) = val;
    }
}

// ---- zero fill ----
__global__ void zero_kernel(int* __restrict__ p, int n)
{
    int i = blockIdx.x * 256 + threadIdx.x;
    if (i < n) p[i] = 0;
}

// ---- CSR build ----
__global__ void hist_kernel(const int* __restrict__ dst, int* __restrict__ count)
{
    int e = blockIdx.x * 256 + threadIdx.x;
    if (e < NE) atomicAdd(count + dst[e], 1);
}

__launch_bounds__(1024)
__global__ void scan_kernel(const int* __restrict__ count, int* __restrict__ rowptr)
{
    __shared__ int part[1024];
    const int t = threadIdx.x;
    const int CH = (NN + 1023) / 1024;          // 30
    const int base = t * CH;
    int sum = 0;
    for (int j = 0; j < CH; j++) {
        int idx = base + j;
        if (idx < NN) sum += count[idx];
    }
    part[t] = sum;
    __syncthreads();
    for (int d = 1; d < 1024; d <<= 1) {
        int v = (t >= d) ? part[t - d] : 0;
        __syncthreads();
        part[t] += v;
        __syncthreads();
    }
    int off = (t == 0) ? 0 : part[t - 1];
    for (int j = 0; j < CH; j++) {
        int idx = base + j;
        if (idx < NN) { rowptr[idx] = off; off += count[idx]; }
    }
    if (t == 1023) rowptr[NN] = part[1023];
}

__global__ void scatter_kernel(const int* __restrict__ src, const int* __restrict__ dst,
                               const int* __restrict__ rowptr, int* __restrict__ cursor,
                               int* __restrict__ src_csr, int* __restrict__ eidx_csr)
{
    int e = blockIdx.x * 256 + threadIdx.x;
    if (e >= NE) return;
    int d = dst[e];
    int pos = rowptr[d] + atomicAdd(cursor + d, 1);
    src_csr[pos] = src[e];
    eidx_csr[pos] = e;
}

// ---- fused aggregation v5: bf16 hp gather, masked 4-edge groups, 2 waves per node,
// residual from hp (bf16) — no fp32 hres stream ----
__device__ __forceinline__ void updm(float hv, float av, float tt, float m,
                                     float& s, float& n)
{
    float g = fmaxf(hv + av, 0.f) + 1e-7f;   // msg
    float e = __expf(g * tt) * m;             // exp(logit), masked
    s += e;
    n = fmaf(g, e, n);
}

__launch_bounds__(256)
__global__ void agg_kernel(const unsigned* __restrict__ hp,
                           const uint4* __restrict__ ea4q, const int* __restrict__ src_csr,
                           const int* __restrict__ rowptr, const float* __restrict__ tptr,
                           int layer, unsigned* __restrict__ Zp)
{
    __shared__ float4 part[4][64];
    const int wv = threadIdx.x >> 6;
    const int node = blockIdx.x * 2 + (wv >> 1);   // grid = NN/2 exact
    const int par = wv & 1;
    const int lane = threadIdx.x & 63;
    const float tt = tptr[layer];
    const int start = rowptr[node];
    const int end = rowptr[node + 1];
    const int g0 = start >> 2, g1 = (end + 3) >> 2;
    float s0a = 0.f, s1a = 0.f, n0a = 0.f, n1a = 0.f;
    float s0b = 0.f, s1b = 0.f, n0b = 0.f, n1b = 0.f;

#define PROC(GG, S0, S1, N0, N1)                                                   \
    {                                                                              \
        uint4 uu = ea4q[((size_t)(GG) << 6) + lane];                               \
        int4 sv = *(const int4*)(src_csr + 4 * (GG));                              \
        int jb = 4 * (GG);                                                         \
        float m0 = (jb     >= start && jb     < end) ? 1.f : 0.f;                  \
        float m1 = (jb + 1 >= start && jb + 1 < end) ? 1.f : 0.f;                  \
        float m2 = (jb + 2 >= start && jb + 2 < end) ? 1.f : 0.f;                  \
        float m3 = (jb + 3 >= start && jb + 3 < end) ? 1.f : 0.f;                  \
        unsigned ha = hp[(size_t)sv.x * 64 + lane];                                \
        unsigned hb = hp[(size_t)sv.y * 64 + lane];                                \
        unsigned hc = hp[(size_t)sv.z * 64 + lane];                                \
        unsigned hd = hp[(size_t)sv.w * 64 + lane];                                \
        updm(__uint_as_float(ha << 16), __uint_as_float(uu.x << 16), tt, m0, S0, N0); \
        updm(__uint_as_float(ha & 0xffff0000u), __uint_as_float(uu.x & 0xffff0000u), tt, m0, S1, N1); \
        updm(__uint_as_float(hb << 16), __uint_as_float(uu.y << 16), tt, m1, S0, N0); \
        updm(__uint_as_float(hb & 0xffff0000u), __uint_as_float(uu.y & 0xffff0000u), tt, m1, S1, N1); \
        updm(__uint_as_float(hc << 16), __uint_as_float(uu.z << 16), tt, m2, S0, N0); \
        updm(__uint_as_float(hc & 0xffff0000u), __uint_as_float(uu.z & 0xffff0000u), tt, m2, S1, N1); \
        updm(__uint_as_float(hd << 16), __uint_as_float(uu.w << 16), tt, m3, S0, N0); \
        updm(__uint_as_float(hd & 0xffff0000u), __uint_as_float(uu.w & 0xffff0000u), tt, m3, S1, N1); \
    }

    int g = g0 + par;                 // this wave takes groups of its parity
    for (; g + 2 < g1; g += 4) {
        PROC(g, s0a, s1a, n0a, n1a);
        PROC(g + 2, s0b, s1b, n0b, n1b);
    }
    if (g < g1) PROC(g, s0a, s1a, n0a, n1a);
#undef PROC
    float ps0 = s0a + s0b, ps1 = s1a + s1b, pn0 = n0a + n0b, pn1 = n1a + n1b;
    part[wv][lane] = make_float4(ps0, ps1, pn0, pn1);
    __syncthreads();
    if (par == 0) {
        float4 o = part[wv + 1][lane];
        float s0 = ps0 + o.x, s1 = ps1 + o.y;
        float n0 = pn0 + o.z, n1 = pn1 + o.w;
        unsigned ur = hp[(size_t)node * 64 + lane];    // residual (bf16 pair)
        float ox = n0 / (s0 + 1e-16f) + __uint_as_float(ur << 16);
        float oy = n1 / (s1 + 1e-16f) + __uint_as_float(ur & 0xffff0000u);
        Zp[(size_t)node * 64 + lane] =
            (unsigned)(unsigned short)f2bs(ox) | ((unsigned)(unsigned short)f2bs(oy) << 16);
    }
}

// ---- fused layer MLP v7: 256 threads, 4 row-tiles/block, LDS-staged weights (XOR swizzle),
// wave-private LN, single-bf16 A/z1. !FINAL: writes h (fp32, next res) + hp (packed relu-LN).
// FINAL: classifier fused — y staged split in wave-private LDS, K=128 MFMA vs lw, d_out direct.
template<bool HAS_RES, bool FINAL>
__launch_bounds__(256)
__global__ void mlp_fused(const short* __restrict__ Ap,
                          const short* __restrict__ B1h, const short* __restrict__ B1l,
                          const float* __restrict__ b1, const float* __restrict__ g1,
                          const float* __restrict__ be1,
                          const short* __restrict__ B2h, const short* __restrict__ B2l,
                          const float* __restrict__ b2, const float* __restrict__ res,
                          const float* __restrict__ g2, const float* __restrict__ be2,
                          short* __restrict__ z1h,
                          float* __restrict__ Hout, unsigned* __restrict__ HP,
                          const short* __restrict__ lwh, const short* __restrict__ lwl,
                          const float* __restrict__ lb, float* __restrict__ Dout)
{
    __shared__ __align__(16) short lds[32768];   // 64 KB: [0:16384]=hi, [16384:]=lo
    const int wv = threadIdx.x >> 6;
    const int lane = threadIdx.x & 63;
    const int l15 = lane & 15, quad = lane >> 4;
    const int tile = blockIdx.x * 4 + wv;
    const bool valid = (tile < NROWT);
    const int row = tile * 16 + l15;

    // ---- phase 1: K=128, N=256 in two 128-col halves; A single bf16 ----
    floatx4 acc[16];
#pragma unroll
    for (int t = 0; t < 16; t++) acc[t] = {0.f, 0.f, 0.f, 0.f};
    for (int hf = 0; hf < 2; hf++) {
        __syncthreads();
        {
            const float4* s1p = (const float4*)(B1h + hf * 16384);
            const float4* s2p = (const float4*)(B1l + hf * 16384);
            float4* d = (float4*)lds;
#pragma unroll
            for (int i = 0; i < 8; i++) {
                int t8 = threadIdx.x + 256 * i;                  // 0..2047
                int col = t8 >> 4, k8 = t8 & 15;
                int unit = col * 16 + (k8 ^ (col & 15));
                d[unit] = s1p[t8];
                d[2048 + unit] = s2p[t8];
            }
        }
        __syncthreads();
        if (valid) {
#pragma unroll
            for (int k0 = 0; k0 < 128; k0 += 32) {
                const int kb = k0 + quad * 8;
                const int kb8 = kb >> 3;
                short8 ah = *(const short8*)(Ap + (size_t)row * 128 + kb);
#pragma unroll
                for (int t = 0; t < 8; t++) {
                    int col = t * 16 + l15;
                    int unit = col * 16 + (kb8 ^ (col & 15));
                    const short* bp = lds + unit * 8;
                    short8 bh = *(const short8*)bp;
                    short8 bl = *(const short8*)(bp + 16384);
                    int ti = hf * 8 + t;
                    acc[ti] = __builtin_amdgcn_mfma_f32_16x16x32_bf16(ah, bh, acc[ti], 0, 0, 0);
                    acc[ti] = __builtin_amdgcn_mfma_f32_16x16x32_bf16(ah, bl, acc[ti], 0, 0, 0);
                }
            }
        }
    }
    // ---- LN1 (wave-private: wave owns full 256-col rows) ----
    if (valid) {
#pragma unroll
        for (int t = 0; t < 16; t++) {
            float bv = b1[t * 16 + l15];
#pragma unroll
            for (int r = 0; r < 4; r++) acc[t][r] += bv;
        }
        float s1[4] = {0.f, 0.f, 0.f, 0.f}, s2[4] = {0.f, 0.f, 0.f, 0.f};
#pragma unroll
        for (int t = 0; t < 16; t++)
#pragma unroll
            for (int r = 0; r < 4; r++) { s1[r] += acc[t][r]; s2[r] += acc[t][r] * acc[t][r]; }
#pragma unroll
        for (int m = 1; m <= 8; m <<= 1)
#pragma unroll
            for (int r = 0; r < 4; r++) {
                s1[r] += __shfl_xor(s1[r], m, 64);
                s2[r] += __shfl_xor(s2[r], m, 64);
            }
        float mean[4], rstd[4];
#pragma unroll
        for (int r = 0; r < 4; r++) {
            mean[r] = s1[r] * (1.f / 256.f);
            float var = s2[r] * (1.f / 256.f) - mean[r] * mean[r];
            rstd[r] = rsqrtf(var + 1e-5f);
        }
#pragma unroll
        for (int t = 0; t < 16; t++) {
            int col = t * 16 + l15;
            float gg = g1[col], bb = be1[col];
#pragma unroll
            for (int r = 0; r < 4; r++) {
                float y = fmaxf((acc[t][r] - mean[r]) * rstd[r] * gg + bb, 0.f);
                int ro = tile * 16 + quad * 4 + r;
                z1h[(size_t)ro * 256 + col] = f2bs(y);
            }
        }
    }
    // ---- phase 2: K=256, N=128 in two 64-col halves; A (z1, single bf16) from global ----
    floatx4 acc2[8];
#pragma unroll
    for (int t = 0; t < 8; t++) acc2[t] = {0.f, 0.f, 0.f, 0.f};
    for (int hf = 0; hf < 2; hf++) {
        __syncthreads();
        {
            const float4* s1p = (const float4*)(B2h + hf * 16384);
            const float4* s2p = (const float4*)(B2l + hf * 16384);
            float4* d = (float4*)lds;
#pragma unroll
            for (int i = 0; i < 8; i++) {
                int t8 = threadIdx.x + 256 * i;                  // 0..2047
                int col = t8 >> 5, k8 = t8 & 31;
                int unit = col * 32 + (k8 ^ (col & 15));
                d[unit] = s1p[t8];
                d[2048 + unit] = s2p[t8];
            }
        }
        __syncthreads();
        if (valid) {
#pragma unroll
            for (int k0 = 0; k0 < 256; k0 += 32) {
                const int kb = k0 + quad * 8;
                const int kb8 = kb >> 3;
                short8 zh = *(const short8*)(z1h + (size_t)row * 256 + kb);
#pragma unroll
                for (int t = 0; t < 4; t++) {
                    int col = t * 16 + l15;
                    int unit = col * 32 + (kb8 ^ (col & 15));
                    const short* bp = lds + unit * 8;
                    short8 bh = *(const short8*)bp;
                    short8 bl = *(const short8*)(bp + 16384);
                    int ti = hf * 4 + t;
                    acc2[ti] = __builtin_amdgcn_mfma_f32_16x16x32_bf16(zh, bh, acc2[ti], 0, 0, 0);
                    acc2[ti] = __builtin_amdgcn_mfma_f32_16x16x32_bf16(zh, bl, acc2[ti], 0, 0, 0);
                }
            }
        }
    }
    // ---- LN2 (wave-private, 128 cols) + outputs ----
    if (FINAL) __syncthreads();          // all phase-2 LDS reads done before y staging reuse
    // per-wave classifier tiles (FINAL): stride 136 shorts (272 B, 16B-aligned, 2-way banks)
    short* yh = lds + wv * 2176;
    short* yl = lds + 8704 + wv * 2176;
    if (valid) {
#pragma unroll
        for (int t = 0; t < 8; t++) {
            int col = t * 16 + l15;
            float bv = b2[col];
#pragma unroll
            for (int r = 0; r < 4; r++) {
                acc2[t][r] += bv;
                if (HAS_RES) {
                    int ro = tile * 16 + quad * 4 + r;
                    acc2[t][r] += res[(size_t)ro * 128 + col];
                }
            }
        }
        float s1[4] = {0.f, 0.f, 0.f, 0.f}, s2[4] = {0.f, 0.f, 0.f, 0.f};
#pragma unroll
        for (int t = 0; t < 8; t++)
#pragma unroll
            for (int r = 0; r < 4; r++) { s1[r] += acc2[t][r]; s2[r] += acc2[t][r] * acc2[t][r]; }
#pragma unroll
        for (int m = 1; m <= 8; m <<= 1)
#pragma unroll
            for (int r = 0; r < 4; r++) {
                s1[r] += __shfl_xor(s1[r], m, 64);
                s2[r] += __shfl_xor(s2[r], m, 64);
            }
        float mean[4], rstd[4];
#pragma unroll
        for (int r = 0; r < 4; r++) {
            mean[r] = s1[r] * (1.f / 128.f);
            float var = s2[r] * (1.f / 128.f) - mean[r] * mean[r];
            rstd[r] = rsqrtf(var + 1e-5f);
        }
#pragma unroll
        for (int t = 0; t < 8; t++) {
            int col = t * 16 + l15;
            float gg = g2[col], bb = be2[col];
#pragma unroll
            for (int r = 0; r < 4; r++) {
                int ro = tile * 16 + quad * 4 + r;
                float x = acc2[t][r];
                float y = fmaxf((x - mean[r]) * rstd[r] * gg + bb, 0.f);
                if (FINAL) {
                    short2 sp = split_bf16(y);
                    yh[(quad * 4 + r) * 136 + col] = sp.x;
                    yl[(quad * 4 + r) * 136 + col] = sp.y;
                } else {
                    Hout[(size_t)ro * 128 + col] = x;
                    int yb = (int)(unsigned short)f2bs(y);
                    int ob = __shfl_xor(yb, 1, 64);
                    if ((l15 & 1) == 0)
                        HP[(size_t)ro * 64 + t * 8 + (l15 >> 1)] =
                            (unsigned)yb | ((unsigned)ob << 16);
                }
            }
        }
    }
    // ---- FINAL: classifier GEMM from wave-private LDS y tile, K=128, N=16 (10 real) ----
    if (FINAL && valid) {
        floatx4 accc = {0.f, 0.f, 0.f, 0.f};
#pragma unroll
        for (int k0 = 0; k0 < 128; k0 += 32) {
            const int kb = k0 + quad * 8;
            short8 ah = *(const short8*)(yh + l15 * 136 + kb);
            short8 al = *(const short8*)(yl + l15 * 136 + kb);
            short8 bh = *(const short8*)(lwh + l15 * 128 + kb);
            short8 bl = *(const short8*)(lwl + l15 * 128 + kb);
            accc = __builtin_amdgcn_mfma_f32_16x16x32_bf16(ah, bh, accc, 0, 0, 0);
            accc = __builtin_amdgcn_mfma_f32_16x16x32_bf16(al, bh, accc, 0, 0, 0);
            accc = __builtin_amdgcn_mfma_f32_16x16x32_bf16(ah, bl, accc, 0, 0, 0);
        }
        if (l15 < 10) {
            float bv = lb[l15];
#pragma unroll
            for (int r = 0; r < 4; r++) {
                int ro = tile * 16 + quad * 4 + r;
                Dout[(size_t)ro * 10 + l15] = accc[r] + bv;
            }
        }
    }
}

extern "C" void kernel_launch(void* const* d_in, const int* in_sizes, int n_in,
                              void* d_out, int out_size, void* d_ws, size_t ws_size,
                              hipStream_t stream)
{
    const float* x         = (const float*)d_in[0];
    const float* edge_attr = (const float*)d_in[1];
    const float* nw        = (const float*)d_in[2];
    const float* nb        = (const float*)d_in[3];
    const float* ew        = (const float*)d_in[4];
    const float* eb        = (const float*)d_in[5];
    const float* m1w       = (const float*)d_in[6];
    const float* m1b       = (const float*)d_in[7];
    const float* lng       = (const float*)d_in[8];
    const float* lnb       = (const float*)d_in[9];
    const float* m2w       = (const float*)d_in[10];
    const float* m2b       = (const float*)d_in[11];
    const float* tpr       = (const float*)d_in[12];
    const float* ng        = (const float*)d_in[13];
    const float* nbb       = (const float*)d_in[14];
    const float* lw        = (const float*)d_in[15];
    const float* lb        = (const float*)d_in[16];
    const int* ei  = (const int*)d_in[17];
    const int* src = ei;
    const int* dst = ei + NE;

    // ---- workspace carve (~185 MB) ----
    char* w = (char*)d_ws;
    unsigned* ea4 = (unsigned*)w; w += (size_t)NE * 128 * 2;                  // 122.88 MB
    int* src_csr  = (int*)w; w += (size_t)NE * 4;
    int* eidx_csr = (int*)w; w += (size_t)NE * 4;
    unsigned* hp  = (unsigned*)w; w += (size_t)NN * 64 * 4;                   // 7.68 MB packed bf16
    unsigned* zp  = (unsigned*)w; w += (size_t)NN * 64 * 4;                   // 7.68 MB packed bf16
    float* h   = (float*)w; w += (size_t)NN * 128 * 4;
    short* z1s_h  = (short*)w; w += (size_t)NN * 256 * 2;
    short* ew_h = (short*)w; w += (size_t)128 * 16 * 2;
    short* ew_l = (short*)w; w += (size_t)128 * 16 * 2;
    short* nw_h = (short*)w; w += (size_t)128 * 64 * 2;
    short* nw_l = (short*)w; w += (size_t)128 * 64 * 2;
    short* m1_h = (short*)w; w += (size_t)3 * 256 * 128 * 2;
    short* m1_l = (short*)w; w += (size_t)3 * 256 * 128 * 2;
    short* m2_h = (short*)w; w += (size_t)3 * 128 * 256 * 2;
    short* m2_l = (short*)w; w += (size_t)3 * 128 * 256 * 2;
    short* lw_h = (short*)w; w += (size_t)16 * 128 * 2;
    short* lw_l = (short*)w; w += (size_t)16 * 128 * 2;
    int* count  = (int*)w;   w += (size_t)NN * 4;
    int* cursor = (int*)w;   w += (size_t)NN * 4;
    int* rowptr = (int*)w;   w += (size_t)(NN + 1) * 4;

    // ---- CSR build ----
    zero_kernel<<<(2 * NN + 255) / 256, 256, 0, stream>>>(count, 2 * NN);
    hist_kernel<<<(NE + 255) / 256, 256, 0, stream>>>(dst, count);
    scan_kernel<<<1, 1024, 0, stream>>>(count, rowptr);
    scatter_kernel<<<(NE + 255) / 256, 256, 0, stream>>>(src, dst, rowptr, cursor,
                                                         src_csr, eidx_csr);

    // ---- weight pre-split ----
    presplit_all<<<(208896 + 255) / 256, 256, 0, stream>>>(
        ew, nw, m1w, m2w, lw, ew_h, ew_l, nw_h, nw_l, m1_h, m1_l, m2_h, m2_l, lw_h, lw_l);

    // ---- edge encoder (gathered, 4-edge-interleaved output) + node encoder ----
    gemm_ea<<<NE / 32, 256, 0, stream>>>(edge_attr, eidx_csr, ew_h, ew_l, eb, ea4);
    gemm_a32<64, 128><<<(NN / 16) * 8 / 4, 256, 0, stream>>>(x, nw_h, nw_l, nb, h, hp,
                                                             (NN / 16) * 8);

    const uint4* ea4q = (const uint4*)ea4;
    const int mgrid = (NROWT + 3) / 4;   // 469 blocks, 4 row-tiles each
    for (int layer = 0; layer < 3; ++layer) {
        agg_kernel<<<NN / 2, 256, 0, stream>>>(hp, ea4q, src_csr, rowptr, tpr, layer, zp);
        if (layer == 0) {
            mlp_fused<false, false><<<mgrid, 256, 0, stream>>>(
                (const short*)zp, m1_h, m1_l, m1b, lng, lnb,
                m2_h, m2_l, m2b, nullptr, ng + 128, nbb + 128,
                z1s_h, h, hp, nullptr, nullptr, nullptr, nullptr);
        } else if (layer == 1) {
            mlp_fused<true, false><<<mgrid, 256, 0, stream>>>(
                (const short*)zp, m1_h + 32768, m1_l + 32768, m1b + 256, lng + 256, lnb + 256,
                m2_h + 32768, m2_l + 32768, m2b + 128, h, ng + 256, nbb + 256,
                z1s_h, h, hp, nullptr, nullptr, nullptr, nullptr);
        } else {
            mlp_fused<true, true><<<mgrid, 256, 0, stream>>>(
                (const short*)zp, m1_h + 65536, m1_l + 65536, m1b + 512, lng + 512, lnb + 512,
                m2_h + 65536, m2_l + 65536, m2b + 256, h, ng, nbb,
                z1s_h, nullptr, nullptr, lw_h, lw_l, lb, (float*)d_out);
        }
    }
}